// Round 12
// baseline (165.717 us; speedup 1.0000x reference)
//
#include <hip/hip_runtime.h>
#include <hip/hip_fp16.h>

#define D 128
typedef __attribute__((ext_vector_type(8))) short short8v;
typedef __attribute__((ext_vector_type(4))) float f32x4;
typedef unsigned long long ull;

#define FLAG_X (1ull << 62)
#define FLAG_P (2ull << 62)

// ---- bf16 helpers ----
__device__ __forceinline__ float bf2f(unsigned short u) {
    union { unsigned int i; float f; } v; v.i = ((unsigned int)u) << 16; return v.f;
}
__device__ __forceinline__ unsigned short f2bf(float f) {
    union { float f; unsigned int i; } v; v.f = f;
    unsigned int r = v.i + 0x7FFF + ((v.i >> 16) & 1);
    return (unsigned short)(r >> 16);
}

// ---- fp8 e4m3fn encode, exact RNE ----
__device__ __forceinline__ unsigned int f8e(float f) {
    unsigned int u = __float_as_uint(f);
    unsigned int s = (u >> 24) & 0x80u;
    float a = fabsf(f);
    if (a < 0.015625f) {
        int m = __float2int_rn(a * 512.0f);
        return s | (unsigned int)m;
    }
    a = fminf(a, 448.0f);
    u = __float_as_uint(a);
    unsigned int r = u + 0x7FFFFu + ((u >> 20) & 1u);
    return s | ((r >> 20) - 960u);
}

// ---- fp8 decode via f16 embedding: returns value/256 (x256 folded at the end) ----
__device__ __forceinline__ float f8d(unsigned int b) {
    union { unsigned short u; __half h; } c;
    c.u = (unsigned short)(((b & 0x80u) << 8) | ((b & 0x7fu) << 7));
    return __half2float(c.h);
}
__device__ __forceinline__ float4 dec4(unsigned int u) {
    float4 r;
    r.x = f8d(u & 0xffu);
    r.y = f8d((u >> 8) & 0xffu);
    r.z = f8d((u >> 16) & 0xffu);
    r.w = f8d(u >> 24);
    return r;
}

// ---------------- k_zero: packed bins + scan status flags ----------------
__global__ void k_zero(int4* __restrict__ p, int n4) {
    int stride = gridDim.x * blockDim.x;
    for (int i = blockIdx.x * blockDim.x + threadIdx.x; i < n4; i += stride)
        p[i] = make_int4(0, 0, 0, 0);
}

// ---------------- edge pass MERGED with weight prep (block-range specialization) ----------------
// blocks [0,Eg): edge weight + ONE 64-bit returning atomic (rank hi | fixed-point deg lo)
// blocks [Eg,Eg+64): Wt transpose->bf16 | block Eg+64: w2l fold | rest: atom table->bf16
__global__ void k_edge_pre(const int* __restrict__ ea, const float* __restrict__ bt,
                           const int* __restrict__ col, float* __restrict__ ew,
                           int* __restrict__ rank, ull* __restrict__ packed, int E, int Eg,
                           const float* __restrict__ W1, unsigned short* __restrict__ Wt,
                           const float* __restrict__ W2, const float* __restrict__ b2,
                           const float* __restrict__ linW, const float* __restrict__ linb,
                           float* __restrict__ w2l,
                           const float* __restrict__ at, unsigned short* __restrict__ at16) {
    int b = blockIdx.x, t = threadIdx.x;
    if (b < Eg) {
        int e = b * 256 + t;
        if (e >= E) return;
        float w = bt[ea[3 * e + 0]] + bt[16 + ea[3 * e + 1]] + bt[32 + ea[3 * e + 2]];
        ew[e] = w;
        ull inc = (1ull << 32) | (ull)(unsigned int)__float2int_rn(w * 65536.0f);
        ull old = atomicAdd(&packed[col[e]], inc);
        rank[e] = (int)(old >> 32);
    } else if (b < Eg + 64) {            // Wt[n][k] = bf16(W1[k][n])
        int idx = (b - Eg) * 256 + t;    // 16384
        int nn = idx >> 7, kk = idx & 127;
        Wt[idx] = f2bf(W1[kk * D + nn]);
    } else if (b == Eg + 64) {           // w2l = W2 @ linW ; w2l[D] = b2.linW + lin_b
        if (t < 128) {
            float s = 0.f;
            for (int nn = 0; nn < D; ++nn) s += W2[t * D + nn] * linW[nn];
            w2l[t] = s;
            if (t == 0) {
                float cc = linb[0];
                for (int nn = 0; nn < D; ++nn) cc += b2[nn] * linW[nn];
                w2l[D] = cc;
            }
        }
    } else {                             // atom table fp32 -> bf16 (18432 float4)
        int idx = (b - Eg - 65) * 256 + t;
        if (idx < 18432) {
            float4 v = ((const float4*)at)[idx];
            ushort4 o;
            o.x = f2bf(v.x); o.y = f2bf(v.y); o.z = f2bf(v.z); o.w = f2bf(v.w);
            ((ushort4*)at16)[idx] = o;
        }
    }
}

// ---------------- single-pass scan (decoupled lookback) + node encode ----------------
// blocks [0,nb): exclusive scan of counts via lookback on stat[] (value rides in flag word).
// blocks [nb,..): dinv from packed deg; g = dinv*AtomEnc(x) -> fp8. Node blocks never spin.
#define SCAN_B 256
__global__ __launch_bounds__(256) void k_scan_node(
        const ull* __restrict__ packed, int* __restrict__ off, ull* __restrict__ stat,
        int n, int E, int nb,
        const int* __restrict__ x, const unsigned short* __restrict__ at16,
        float* __restrict__ dinv, unsigned int* __restrict__ h8) {
    int b = blockIdx.x, tid = threadIdx.x;
    if (b < nb) {
        __shared__ int s[SCAN_B];
        __shared__ int sbase;
        int i = b * SCAN_B + tid;
        int v = (i < n) ? (int)(packed[i] >> 32) : 0;
        s[tid] = v;
        __syncthreads();
        for (int o = 1; o < SCAN_B; o <<= 1) {
            int t2 = (tid >= o) ? s[tid - o] : 0;
            __syncthreads();
            s[tid] += t2;
            __syncthreads();
        }
        int incl = s[tid];
        int A = s[SCAN_B - 1];
        if (tid == 0) {
            if (b == 0) {
                __threadfence();
                *(volatile ull*)&stat[0] = FLAG_P | (unsigned int)A;
                sbase = 0;
            } else {
                __threadfence();
                *(volatile ull*)&stat[b] = FLAG_X | (unsigned int)A;
                ull run = 0;
                int j = b - 1;
                while (true) {
                    ull vv = *(volatile ull*)&stat[j];
                    ull fl = vv >> 62;
                    if (fl == 2ull) { run += (vv & 0xffffffffull); break; }
                    if (fl == 1ull) { run += (vv & 0xffffffffull); --j; }
                }
                __threadfence();
                *(volatile ull*)&stat[b] = FLAG_P | (run + (unsigned int)A);
                sbase = (int)run;
            }
        }
        __syncthreads();
        int base = sbase;
        if (i < n) off[i] = base + incl - v;   // exclusive prefix
        if (b == 0 && tid == 0) off[n] = E;    // sentinel
        return;
    }
    int node = (b - nb) * 8 + (tid >> 5);
    int q = tid & 31;
    if (node >= n) return;
    unsigned int degfix = (unsigned int)(packed[node] & 0xffffffffull);
    float d = 1.0f + (float)degfix * (1.0f / 65536.0f);  // self loop + Sum(ew)
    float di = rsqrtf(d);
    if (q == 0) dinv[node] = di;
    const int* xr = x + node * 9;
    float sx = 0.f, sy = 0.f, sz = 0.f, sw = 0.f;
#pragma unroll
    for (int f = 0; f < 9; ++f) {
        ushort4 v = *(const ushort4*)(at16 + (long)(xr[f] + f * 64) * D + q * 4);
        sx += bf2f(v.x); sy += bf2f(v.y); sz += bf2f(v.z); sw += bf2f(v.w);
    }
    unsigned int p = f8e(sx * di) | (f8e(sy * di) << 8) | (f8e(sz * di) << 16) | (f8e(sw * di) << 24);
    h8[(long)node * 32 + q] = p;
}

// ---------------- CSR fill (no atomics): csr = (row, ew) ----------------
__global__ void k_fill(const int* __restrict__ row, const int* __restrict__ col,
                       const int* __restrict__ rank, const int* __restrict__ off,
                       const float* __restrict__ ew, int2* __restrict__ csr, int E) {
    int e = blockIdx.x * blockDim.x + threadIdx.x;
    if (e >= E) return;
    int p = off[col[e]] + rank[e];
    int2 v;
    v.x = row[e];
    v.y = __float_as_int(ew[e]);
    csr[p] = v;
}

// ---------------- gather1: out1[c] = dinv[c]*(g[c] + sum ew*g[r]), fp8 in, bf16 out ----------------
__global__ void k_gather1(const unsigned int* __restrict__ h8, const int* __restrict__ off,
                          const int2* __restrict__ csr, const float* __restrict__ dinv,
                          unsigned short* __restrict__ outh, int n) {
    int node = blockIdx.x * 8 + (threadIdx.x >> 5);
    int q = threadIdx.x & 31;
    if (node >= n) return;
    int o = off[node], oe = off[node + 1];
    float4 sf = dec4(h8[(long)node * 32 + q]);
    float ax0 = sf.x, ay0 = sf.y, az0 = sf.z, aw0 = sf.w;   // self term, weight 1
    float ax1 = 0.f, ay1 = 0.f, az1 = 0.f, aw1 = 0.f;
    int k = o;
    for (; k + 4 <= oe; k += 4) {
        int2 p0 = csr[k], p1 = csr[k + 1], p2 = csr[k + 2], p3 = csr[k + 3];
        unsigned int u0 = h8[(long)p0.x * 32 + q];
        unsigned int u1 = h8[(long)p1.x * 32 + q];
        unsigned int u2 = h8[(long)p2.x * 32 + q];
        unsigned int u3 = h8[(long)p3.x * 32 + q];
        float w0 = __int_as_float(p0.y), w1 = __int_as_float(p1.y);
        float w2 = __int_as_float(p2.y), w3 = __int_as_float(p3.y);
        float4 f0 = dec4(u0), f1 = dec4(u1), f2 = dec4(u2), f3 = dec4(u3);
        ax0 += f0.x * w0 + f1.x * w1; ax1 += f2.x * w2 + f3.x * w3;
        ay0 += f0.y * w0 + f1.y * w1; ay1 += f2.y * w2 + f3.y * w3;
        az0 += f0.z * w0 + f1.z * w1; az1 += f2.z * w2 + f3.z * w3;
        aw0 += f0.w * w0 + f1.w * w1; aw1 += f2.w * w2 + f3.w * w3;
    }
    for (; k < oe; ++k) {
        int2 p0 = csr[k];
        float w0 = __int_as_float(p0.y);
        float4 f0 = dec4(h8[(long)p0.x * 32 + q]);
        ax0 += f0.x * w0;
        ay0 += f0.y * w0;
        az0 += f0.z * w0;
        aw0 += f0.w * w0;
    }
    float s256 = dinv[node] * 256.0f;   // undo /256 decode + apply dinv[c]
    ushort4 ov;
    ov.x = f2bf((ax0 + ax1) * s256); ov.y = f2bf((ay0 + ay1) * s256);
    ov.z = f2bf((az0 + az1) * s256); ov.w = f2bf((aw0 + aw1) * s256);
    *(ushort4*)(outh + (long)node * D + q * 4) = ov;
}

// ---------------- MFMA matmul + fused scalar projection: t[r] = dinv[r]*(relu(A@W1+b1).w2l) ----------------
__global__ __launch_bounds__(256) void k_mm1(const unsigned short* __restrict__ A,
                                             const unsigned short* __restrict__ Wt,
                                             const float* __restrict__ bias,
                                             const float* __restrict__ w2l,
                                             const float* __restrict__ dinv,
                                             float* __restrict__ tOut, int n) {
    const int tid = threadIdx.x;
    const int w = tid >> 6, l = tid & 63;
    const int lm = l & 15, lk = l >> 4;
    const long rbase = (long)blockIdx.x * 128 + w * 32;
    f32x4 acc[2][8] = {};
#pragma unroll
    for (int kc = 0; kc < 4; ++kc) {
        short8v bfr[8];
#pragma unroll
        for (int ct = 0; ct < 8; ++ct)
            bfr[ct] = *(const short8v*)(Wt + (long)(ct * 16 + lm) * D + kc * 32 + lk * 8);
#pragma unroll
        for (int rt = 0; rt < 2; ++rt) {
            long r = rbase + rt * 16 + lm;
            if (r >= n) r = n - 1;
            short8v afr = *(const short8v*)(A + r * D + kc * 32 + lk * 8);
#pragma unroll
            for (int ct = 0; ct < 8; ++ct)
                acc[rt][ct] = __builtin_amdgcn_mfma_f32_16x16x32_bf16(afr, bfr[ct], acc[rt][ct], 0, 0, 0);
        }
    }
    float bcol[8], wcol[8];
#pragma unroll
    for (int ct = 0; ct < 8; ++ct) {
        bcol[ct] = bias[ct * 16 + lm];
        wcol[ct] = w2l[ct * 16 + lm];
    }
    float p[2][4] = {};
#pragma unroll
    for (int rt = 0; rt < 2; ++rt)
#pragma unroll
        for (int ct = 0; ct < 8; ++ct)
#pragma unroll
            for (int j = 0; j < 4; ++j)
                p[rt][j] += fmaxf(acc[rt][ct][j] + bcol[ct], 0.f) * wcol[ct];
#pragma unroll
    for (int m = 1; m < 16; m <<= 1) {
#pragma unroll
        for (int rt = 0; rt < 2; ++rt)
#pragma unroll
            for (int j = 0; j < 4; ++j)
                p[rt][j] += __shfl_xor(p[rt][j], m);
    }
    if (lm == 0) {
#pragma unroll
        for (int rt = 0; rt < 2; ++rt)
#pragma unroll
            for (int j = 0; j < 4; ++j) {
                long r = rbase + rt * 16 + lk * 4 + j;
                if (r < n) tOut[r] = p[rt][j] * dinv[r];
            }
    }
}

// ---------------- gather2 scalar: out[v] = sigmoid(dinv[v]*(t[v] + sum ew*t[r]) + c) ----------------
__global__ void k_gather2s(const float* __restrict__ t, const int* __restrict__ off,
                           const int2* __restrict__ csr, const float* __restrict__ dinv,
                           const float* __restrict__ w2l, float* __restrict__ out, int n) {
    int v = blockIdx.x * blockDim.x + threadIdx.x;
    if (v >= n) return;
    int o = off[v], oe = off[v + 1];
    float a = t[v];   // self term
    int k = o;
    for (; k + 2 <= oe; k += 2) {
        int2 p0 = csr[k], p1 = csr[k + 1];
        a += __int_as_float(p0.y) * t[p0.x];
        a += __int_as_float(p1.y) * t[p1.x];
    }
    if (k < oe) {
        int2 p0 = csr[k];
        a += __int_as_float(p0.y) * t[p0.x];
    }
    out[v] = 1.f / (1.f + expf(-(dinv[v] * a + w2l[D])));
}

extern "C" void kernel_launch(void* const* d_in, const int* in_sizes, int n_in,
                              void* d_out, int out_size, void* d_ws, size_t ws_size,
                              hipStream_t stream) {
    const int* x          = (const int*)d_in[0];
    const int* edge_index = (const int*)d_in[1];
    const int* edge_attr  = (const int*)d_in[2];
    const float* atom_table = (const float*)d_in[3];
    const float* bond_table = (const float*)d_in[4];
    const float* W1 = (const float*)d_in[5];
    const float* b1 = (const float*)d_in[6];
    const float* W2 = (const float*)d_in[7];
    const float* b2 = (const float*)d_in[8];
    const float* lin_W = (const float*)d_in[9];
    const float* lin_b = (const float*)d_in[10];
    float* out = (float*)d_out;

    const int N = in_sizes[0] / 9;
    const int E = in_sizes[1] / 2;
    const int* row = edge_index;
    const int* col = edge_index + E;

    float* ws = (float*)d_ws;
    float* ew    = ws;                          // E
    float* dinv  = ew + E;                      // N
    ull*   packed = (ull*)(dinv + N);           // N (8B aligned: E+N even)
    int*   off   = (int*)(packed + N);          // N+2
    int*   rank  = off + N + 2;                 // E
    ull*   stat  = (ull*)(rank + E);            // 512 (offset ints 2E+3N+2: even -> aligned)
    int2*  csr   = (int2*)(stat + 512);         // E int2
    float* w2l   = (float*)(csr + E);           // 132
    float* tbuf  = w2l + 132;                   // N
    unsigned short* W1t  = (unsigned short*)(tbuf + N);   // 16384
    unsigned short* at16 = W1t + 16384;                   // 73728
    unsigned int*   h8   = (unsigned int*)(at16 + 73728); // N*32
    unsigned short* hB   = (unsigned short*)(h8 + 32 * (long)N);  // N*D bf16

    const int nb = (N + SCAN_B - 1) / SCAN_B;
    const int egrid = (E + 255) / 256;
    const int ngrid = (N + 255) / 256;
    const int nodeb = (N + 7) / 8;

    // 7-launch pipeline
    k_zero<<<128, 256, 0, stream>>>((int4*)packed, N / 2);          // packed N*8B ...
    // (stat flags are zeroed by the same kernel via contiguity? NO -- zero separately below)
    k_zero<<<2, 256, 0, stream>>>((int4*)stat, 256);                // stat 512*8B
    k_edge_pre<<<egrid + 137, 256, 0, stream>>>(edge_attr, bond_table, col, ew, rank,
                                                packed, E, egrid,
                                                W1, W1t, W2, b2, lin_W, lin_b, w2l,
                                                atom_table, at16);
    k_scan_node<<<nb + nodeb, 256, 0, stream>>>(packed, off, stat, N, E, nb,
                                                x, at16, dinv, h8);
    k_fill<<<egrid, 256, 0, stream>>>(row, col, rank, off, ew, csr, E);
    k_gather1<<<nodeb, 256, 0, stream>>>(h8, off, csr, dinv, hB, N);
    k_mm1<<<(N + 127) / 128, 256, 0, stream>>>(hB, W1t, b1, w2l, dinv, tbuf, N);
    k_gather2s<<<ngrid, 256, 0, stream>>>(tbuf, off, csr, dinv, w2l, out, N);
}

// Round 13
// 141.336 us; speedup vs baseline: 1.1725x; 1.1725x over previous
//
#include <hip/hip_runtime.h>
#include <hip/hip_fp16.h>

#define D 128
typedef __attribute__((ext_vector_type(8))) short short8v;
typedef __attribute__((ext_vector_type(4))) float f32x4;
typedef unsigned long long ull;

// ---- bf16 helpers ----
__device__ __forceinline__ float bf2f(unsigned short u) {
    union { unsigned int i; float f; } v; v.i = ((unsigned int)u) << 16; return v.f;
}
__device__ __forceinline__ unsigned short f2bf(float f) {
    union { float f; unsigned int i; } v; v.f = f;
    unsigned int r = v.i + 0x7FFF + ((v.i >> 16) & 1);
    return (unsigned short)(r >> 16);
}

// ---- fp8 e4m3fn encode, exact RNE ----
__device__ __forceinline__ unsigned int f8e(float f) {
    unsigned int u = __float_as_uint(f);
    unsigned int s = (u >> 24) & 0x80u;
    float a = fabsf(f);
    if (a < 0.015625f) {
        int m = __float2int_rn(a * 512.0f);
        return s | (unsigned int)m;
    }
    a = fminf(a, 448.0f);
    u = __float_as_uint(a);
    unsigned int r = u + 0x7FFFFu + ((u >> 20) & 1u);
    return s | ((r >> 20) - 960u);
}

// ---- fp8 decode via f16 embedding: returns value/256 (x256 folded at the end) ----
__device__ __forceinline__ float f8d(unsigned int b) {
    union { unsigned short u; __half h; } c;
    c.u = (unsigned short)(((b & 0x80u) << 8) | ((b & 0x7fu) << 7));
    return __half2float(c.h);
}
__device__ __forceinline__ float4 dec4(unsigned int u) {
    float4 r;
    r.x = f8d(u & 0xffu);
    r.y = f8d((u >> 8) & 0xffu);
    r.z = f8d((u >> 16) & 0xffu);
    r.w = f8d(u >> 24);
    return r;
}

// ---------------- k_zero: packed bins ----------------
__global__ void k_zero(int4* __restrict__ p, int n4) {
    int stride = gridDim.x * blockDim.x;
    for (int i = blockIdx.x * blockDim.x + threadIdx.x; i < n4; i += stride)
        p[i] = make_int4(0, 0, 0, 0);
}

// ---------------- edge pass MERGED with weight prep (block-range specialization) ----------------
// blocks [0,Eg): edge weight + ONE 64-bit returning atomic (rank hi | fixed-point deg lo)
// blocks [Eg,Eg+64): Wt transpose->bf16 | block Eg+64: w2l fold | rest: atom table->bf16
__global__ void k_edge_pre(const int* __restrict__ ea, const float* __restrict__ bt,
                           const int* __restrict__ col, float* __restrict__ ew,
                           int* __restrict__ rank, ull* __restrict__ packed, int E, int Eg,
                           const float* __restrict__ W1, unsigned short* __restrict__ Wt,
                           const float* __restrict__ W2, const float* __restrict__ b2,
                           const float* __restrict__ linW, const float* __restrict__ linb,
                           float* __restrict__ w2l,
                           const float* __restrict__ at, unsigned short* __restrict__ at16) {
    int b = blockIdx.x, t = threadIdx.x;
    if (b < Eg) {
        int e = b * 256 + t;
        if (e >= E) return;
        float w = bt[ea[3 * e + 0]] + bt[16 + ea[3 * e + 1]] + bt[32 + ea[3 * e + 2]];
        ew[e] = w;
        ull inc = (1ull << 32) | (ull)(unsigned int)__float2int_rn(w * 65536.0f);
        ull old = atomicAdd(&packed[col[e]], inc);
        rank[e] = (int)(old >> 32);
    } else if (b < Eg + 64) {            // Wt[n][k] = bf16(W1[k][n])
        int idx = (b - Eg) * 256 + t;    // 16384
        int nn = idx >> 7, kk = idx & 127;
        Wt[idx] = f2bf(W1[kk * D + nn]);
    } else if (b == Eg + 64) {           // w2l = W2 @ linW ; w2l[D] = b2.linW + lin_b
        if (t < 128) {
            float s = 0.f;
            for (int nn = 0; nn < D; ++nn) s += W2[t * D + nn] * linW[nn];
            w2l[t] = s;
            if (t == 0) {
                float cc = linb[0];
                for (int nn = 0; nn < D; ++nn) cc += b2[nn] * linW[nn];
                w2l[D] = cc;
            }
        }
    } else {                             // atom table fp32 -> bf16 (18432 float4)
        int idx = (b - Eg - 65) * 256 + t;
        if (idx < 18432) {
            float4 v = ((const float4*)at)[idx];
            ushort4 o;
            o.x = f2bf(v.x); o.y = f2bf(v.y); o.z = f2bf(v.z); o.w = f2bf(v.w);
            ((ushort4*)at16)[idx] = o;
        }
    }
}

// ---------------- scan1: per-block exclusive scan of counts + block totals ----------------
#define SCAN_B 256
__global__ void k_scan1(const ull* __restrict__ packed, int* __restrict__ off,
                        int* __restrict__ bsums, int n) {
    __shared__ int s[SCAN_B];
    int tid = threadIdx.x;
    int i = blockIdx.x * SCAN_B + tid;
    int v = (i < n) ? (int)(packed[i] >> 32) : 0;
    s[tid] = v;
    __syncthreads();
    for (int o = 1; o < SCAN_B; o <<= 1) {
        int t = (tid >= o) ? s[tid - o] : 0;
        __syncthreads();
        s[tid] += t;
        __syncthreads();
    }
    if (i < n) off[i] = s[tid] - v;
    if (tid == SCAN_B - 1) bsums[blockIdx.x] = s[tid];
}

// ---------------- scan23 + node (block-range specialization) ----------------
// blocks [0,nb): finish scan (each block sums bsums[j<b], adds base, sentinel).
// blocks [nb,..): dinv from packed deg; g = dinv*AtomEnc(x) -> fp8.
__global__ __launch_bounds__(256) void k_scan23_node(
        int* __restrict__ off, const int* __restrict__ bsums, int n, int E, int nb,
        const int* __restrict__ x, const unsigned short* __restrict__ at16,
        const ull* __restrict__ packed, float* __restrict__ dinv,
        unsigned int* __restrict__ h8) {
    int b = blockIdx.x, tid = threadIdx.x;
    if (b < nb) {
        int acc = 0;
        for (int j = tid; j < b; j += SCAN_B) acc += bsums[j];
#pragma unroll
        for (int o = 32; o; o >>= 1) acc += __shfl_down(acc, o);
        __shared__ int wsum[4];
        if ((tid & 63) == 0) wsum[tid >> 6] = acc;
        __syncthreads();
        int base = wsum[0] + wsum[1] + wsum[2] + wsum[3];
        int i = b * SCAN_B + tid;
        if (i < n) off[i] += base;
        if (b == 0 && tid == 0) off[n] = E;  // sentinel
        return;
    }
    int node = (b - nb) * 8 + (tid >> 5);
    int q = tid & 31;
    if (node >= n) return;
    unsigned int degfix = (unsigned int)(packed[node] & 0xffffffffull);
    float d = 1.0f + (float)degfix * (1.0f / 65536.0f);  // self loop + Sum(ew)
    float di = rsqrtf(d);
    if (q == 0) dinv[node] = di;
    const int* xr = x + node * 9;
    float sx = 0.f, sy = 0.f, sz = 0.f, sw = 0.f;
#pragma unroll
    for (int f = 0; f < 9; ++f) {
        ushort4 v = *(const ushort4*)(at16 + (long)(xr[f] + f * 64) * D + q * 4);
        sx += bf2f(v.x); sy += bf2f(v.y); sz += bf2f(v.z); sw += bf2f(v.w);
    }
    unsigned int p = f8e(sx * di) | (f8e(sy * di) << 8) | (f8e(sz * di) << 16) | (f8e(sw * di) << 24);
    h8[(long)node * 32 + q] = p;
}

// ---------------- CSR fill (no atomics): csr = (row, ew) ----------------
__global__ void k_fill(const int* __restrict__ row, const int* __restrict__ col,
                       const int* __restrict__ rank, const int* __restrict__ off,
                       const float* __restrict__ ew, int2* __restrict__ csr, int E) {
    int e = blockIdx.x * blockDim.x + threadIdx.x;
    if (e >= E) return;
    int p = off[col[e]] + rank[e];
    int2 v;
    v.x = row[e];
    v.y = __float_as_int(ew[e]);
    csr[p] = v;
}

// ---------------- gather1: out1[c] = dinv[c]*(g[c] + sum ew*g[r]), fp8 in, bf16 out ----------------
__global__ void k_gather1(const unsigned int* __restrict__ h8, const int* __restrict__ off,
                          const int2* __restrict__ csr, const float* __restrict__ dinv,
                          unsigned short* __restrict__ outh, int n) {
    int node = blockIdx.x * 8 + (threadIdx.x >> 5);
    int q = threadIdx.x & 31;
    if (node >= n) return;
    int o = off[node], oe = off[node + 1];
    float4 sf = dec4(h8[(long)node * 32 + q]);
    float ax0 = sf.x, ay0 = sf.y, az0 = sf.z, aw0 = sf.w;   // self term, weight 1
    float ax1 = 0.f, ay1 = 0.f, az1 = 0.f, aw1 = 0.f;
    int k = o;
    for (; k + 4 <= oe; k += 4) {
        int2 p0 = csr[k], p1 = csr[k + 1], p2 = csr[k + 2], p3 = csr[k + 3];
        unsigned int u0 = h8[(long)p0.x * 32 + q];
        unsigned int u1 = h8[(long)p1.x * 32 + q];
        unsigned int u2 = h8[(long)p2.x * 32 + q];
        unsigned int u3 = h8[(long)p3.x * 32 + q];
        float w0 = __int_as_float(p0.y), w1 = __int_as_float(p1.y);
        float w2 = __int_as_float(p2.y), w3 = __int_as_float(p3.y);
        float4 f0 = dec4(u0), f1 = dec4(u1), f2 = dec4(u2), f3 = dec4(u3);
        ax0 += f0.x * w0 + f1.x * w1; ax1 += f2.x * w2 + f3.x * w3;
        ay0 += f0.y * w0 + f1.y * w1; ay1 += f2.y * w2 + f3.y * w3;
        az0 += f0.z * w0 + f1.z * w1; az1 += f2.z * w2 + f3.z * w3;
        aw0 += f0.w * w0 + f1.w * w1; aw1 += f2.w * w2 + f3.w * w3;
    }
    for (; k < oe; ++k) {
        int2 p0 = csr[k];
        float w0 = __int_as_float(p0.y);
        float4 f0 = dec4(h8[(long)p0.x * 32 + q]);
        ax0 += f0.x * w0;
        ay0 += f0.y * w0;
        az0 += f0.z * w0;
        aw0 += f0.w * w0;
    }
    float s256 = dinv[node] * 256.0f;   // undo /256 decode + apply dinv[c]
    ushort4 ov;
    ov.x = f2bf((ax0 + ax1) * s256); ov.y = f2bf((ay0 + ay1) * s256);
    ov.z = f2bf((az0 + az1) * s256); ov.w = f2bf((aw0 + aw1) * s256);
    *(ushort4*)(outh + (long)node * D + q * 4) = ov;
}

// ---------------- MFMA matmul + fused scalar projection: t[r] = dinv[r]*(relu(A@W1+b1).w2l) ----------------
__global__ __launch_bounds__(256) void k_mm1(const unsigned short* __restrict__ A,
                                             const unsigned short* __restrict__ Wt,
                                             const float* __restrict__ bias,
                                             const float* __restrict__ w2l,
                                             const float* __restrict__ dinv,
                                             float* __restrict__ tOut, int n) {
    const int tid = threadIdx.x;
    const int w = tid >> 6, l = tid & 63;
    const int lm = l & 15, lk = l >> 4;
    const long rbase = (long)blockIdx.x * 128 + w * 32;
    f32x4 acc[2][8] = {};
#pragma unroll
    for (int kc = 0; kc < 4; ++kc) {
        short8v bfr[8];
#pragma unroll
        for (int ct = 0; ct < 8; ++ct)
            bfr[ct] = *(const short8v*)(Wt + (long)(ct * 16 + lm) * D + kc * 32 + lk * 8);
#pragma unroll
        for (int rt = 0; rt < 2; ++rt) {
            long r = rbase + rt * 16 + lm;
            if (r >= n) r = n - 1;
            short8v afr = *(const short8v*)(A + r * D + kc * 32 + lk * 8);
#pragma unroll
            for (int ct = 0; ct < 8; ++ct)
                acc[rt][ct] = __builtin_amdgcn_mfma_f32_16x16x32_bf16(afr, bfr[ct], acc[rt][ct], 0, 0, 0);
        }
    }
    float bcol[8], wcol[8];
#pragma unroll
    for (int ct = 0; ct < 8; ++ct) {
        bcol[ct] = bias[ct * 16 + lm];
        wcol[ct] = w2l[ct * 16 + lm];
    }
    float p[2][4] = {};
#pragma unroll
    for (int rt = 0; rt < 2; ++rt)
#pragma unroll
        for (int ct = 0; ct < 8; ++ct)
#pragma unroll
            for (int j = 0; j < 4; ++j)
                p[rt][j] += fmaxf(acc[rt][ct][j] + bcol[ct], 0.f) * wcol[ct];
#pragma unroll
    for (int m = 1; m < 16; m <<= 1) {
#pragma unroll
        for (int rt = 0; rt < 2; ++rt)
#pragma unroll
            for (int j = 0; j < 4; ++j)
                p[rt][j] += __shfl_xor(p[rt][j], m);
    }
    if (lm == 0) {
#pragma unroll
        for (int rt = 0; rt < 2; ++rt)
#pragma unroll
            for (int j = 0; j < 4; ++j) {
                long r = rbase + rt * 16 + lk * 4 + j;
                if (r < n) tOut[r] = p[rt][j] * dinv[r];
            }
    }
}

// ---------------- gather2 scalar: out[v] = sigmoid(dinv[v]*(t[v] + sum ew*t[r]) + c) ----------------
__global__ void k_gather2s(const float* __restrict__ t, const int* __restrict__ off,
                           const int2* __restrict__ csr, const float* __restrict__ dinv,
                           const float* __restrict__ w2l, float* __restrict__ out, int n) {
    int v = blockIdx.x * blockDim.x + threadIdx.x;
    if (v >= n) return;
    int o = off[v], oe = off[v + 1];
    float a = t[v];   // self term
    int k = o;
    for (; k + 2 <= oe; k += 2) {
        int2 p0 = csr[k], p1 = csr[k + 1];
        a += __int_as_float(p0.y) * t[p0.x];
        a += __int_as_float(p1.y) * t[p1.x];
    }
    if (k < oe) {
        int2 p0 = csr[k];
        a += __int_as_float(p0.y) * t[p0.x];
    }
    out[v] = 1.f / (1.f + expf(-(dinv[v] * a + w2l[D])));
}

extern "C" void kernel_launch(void* const* d_in, const int* in_sizes, int n_in,
                              void* d_out, int out_size, void* d_ws, size_t ws_size,
                              hipStream_t stream) {
    const int* x          = (const int*)d_in[0];
    const int* edge_index = (const int*)d_in[1];
    const int* edge_attr  = (const int*)d_in[2];
    const float* atom_table = (const float*)d_in[3];
    const float* bond_table = (const float*)d_in[4];
    const float* W1 = (const float*)d_in[5];
    const float* b1 = (const float*)d_in[6];
    const float* W2 = (const float*)d_in[7];
    const float* b2 = (const float*)d_in[8];
    const float* lin_W = (const float*)d_in[9];
    const float* lin_b = (const float*)d_in[10];
    float* out = (float*)d_out;

    const int N = in_sizes[0] / 9;
    const int E = in_sizes[1] / 2;
    const int* row = edge_index;
    const int* col = edge_index + E;

    float* ws = (float*)d_ws;
    float* ew    = ws;                          // E
    float* dinv  = ew + E;                      // N
    ull*   packed = (ull*)(dinv + N);           // N (8B aligned: E+N even)
    int*   off   = (int*)(packed + N);          // N+2
    int*   rank  = off + N + 2;                 // E
    int*   bsums = rank + E;                    // 512
    int2*  csr   = (int2*)(bsums + 512);        // E int2
    float* w2l   = (float*)(csr + E);           // 132
    float* tbuf  = w2l + 132;                   // N
    unsigned short* W1t  = (unsigned short*)(tbuf + N);   // 16384
    unsigned short* at16 = W1t + 16384;                   // 73728
    unsigned int*   h8   = (unsigned int*)(at16 + 73728); // N*32
    unsigned short* hB   = (unsigned short*)(h8 + 32 * (long)N);  // N*D bf16

    const int nb = (N + SCAN_B - 1) / SCAN_B;
    const int egrid = (E + 255) / 256;
    const int ngrid = (N + 255) / 256;
    const int nodeb = (N + 7) / 8;

    // 8-launch pipeline
    k_zero<<<128, 256, 0, stream>>>((int4*)packed, N / 2);
    k_edge_pre<<<egrid + 137, 256, 0, stream>>>(edge_attr, bond_table, col, ew, rank,
                                                packed, E, egrid,
                                                W1, W1t, W2, b2, lin_W, lin_b, w2l,
                                                atom_table, at16);
    k_scan1<<<nb, SCAN_B, 0, stream>>>(packed, off, bsums, N);
    k_scan23_node<<<nb + nodeb, 256, 0, stream>>>(off, bsums, N, E, nb,
                                                  x, at16, packed, dinv, h8);
    k_fill<<<egrid, 256, 0, stream>>>(row, col, rank, off, ew, csr, E);
    k_gather1<<<nodeb, 256, 0, stream>>>(h8, off, csr, dinv, hB, N);
    k_mm1<<<(N + 127) / 128, 256, 0, stream>>>(hB, W1t, b1, w2l, dinv, tbuf, N);
    k_gather2s<<<ngrid, 256, 0, stream>>>(tbuf, off, csr, dinv, w2l, out, N);
}